// Round 6
// baseline (172.123 us; speedup 1.0000x reference)
//
#include <hip/hip_runtime.h>
#include <cstdint>
#include <cstddef>

#define N_INST 131072
#define D_EMB  512
#define ATT    128
#define NBAGS  256
#define TILE_I 64
#define KC     128
#define LDAc   136   // padded bf16 row stride for KC chunk (272 B)

typedef __attribute__((ext_vector_type(8))) short  bf16x8;
typedef __attribute__((ext_vector_type(4))) float  f32x4;
typedef __attribute__((ext_vector_type(4))) unsigned short u16x4;

// ---------------- workspace layout (floats) ----------------
// [0] Z1, [1] Z2
// [16..528)     v[512]     = W_c @ w_out (folded classifier)
// [1024..1280)  e2[256]
// [1536..2048)  outer[512]
// [4096..36864) Wt bf16 [128][512] (W_a1 transposed, n-major; 65536 bf16)
// [36864..1085440)  rawr[8][256][512]  (replica-sharded bag accumulators)
// [1085440..1216512) sval_g[131072]    (per-instance exp(sigmoid(att)))

__device__ inline unsigned short f2b(float f) {
    unsigned u = __builtin_bit_cast(unsigned, f);
    u += 0x7FFFu + ((u >> 16) & 1u);          // RNE
    return (unsigned short)(u >> 16);
}

__device__ inline float fast_tanh(float x) {
    float e = __expf(2.f * x);                // +inf/0 at extremes -> exact +-1
    return 1.f - 2.f / (e + 1.f);
}

// ============ prep: Wt[n][k] = bf16(W_a1[k][n]) ============
__global__ __launch_bounds__(256) void k_prep_wt(
    const float* __restrict__ Wa1, unsigned short* __restrict__ Wt)
{
    const int n = blockIdx.x;
    for (int k = threadIdx.x; k < D_EMB; k += 256)
        Wt[(size_t)n * D_EMB + k] = f2b(Wa1[(size_t)k * ATT + n]);
}

// ============ K_score: instance attention scores only ============
// 64 instances/block, 4 waves, KC=128 double-buffered chunks, B-frags
// double-buffered in registers. Fully static 4-chunk pipeline, 1 barrier/chunk.
__global__ __launch_bounds__(256, 3) void k_score(
    const float* __restrict__ emb,
    const unsigned short* __restrict__ Wt, const float* __restrict__ ba1,
    const float* __restrict__ wo1, const float* __restrict__ bo1,
    float* __restrict__ sval_g, float* __restrict__ Z1)
{
    __shared__ unsigned short Ash[2][TILE_I * LDAc];   // 2 x 17408 B
    __shared__ float att4[4][TILE_I];

    const int t  = threadIdx.x;
    const int w  = t >> 6;        // 0..3: wave owns n-cols [32w, 32w+32)
    const int l  = t & 63;
    const int l4 = l & 15;
    const int h4 = l >> 4;        // 0..3
    const size_t i0 = (size_t)blockIdx.x * TILE_I;

    float ba1v[2], wo1v[2];
    #pragma unroll
    for (int nt = 0; nt < 2; ++nt) {
        int c = 16 * (2 * w + nt) + l4;
        ba1v[nt] = ba1[c];
        wo1v[nt] = wo1[c];
    }

    bf16x8 bfA[2][4], bfB[2][4];
    auto loadB = [&](bf16x8 (&dst)[2][4], int k0) {
        #pragma unroll
        for (int nt = 0; nt < 2; ++nt) {
            const int n = 16 * (2 * w + nt) + l4;
            #pragma unroll
            for (int ks = 0; ks < 4; ++ks)
                dst[nt][ks] = *reinterpret_cast<const bf16x8*>(
                    &Wt[(size_t)n * D_EMB + k0 + 32 * ks + 8 * h4]);
        }
    };

    auto stage = [&](int buf, int k0) {
        float4 v[8];
        #pragma unroll
        for (int j = 0; j < 8; ++j) {
            int idx = j * 256 + t;            // float4 idx in [0, 2048)
            int row = idx >> 5;               // 32 float4 per row (KC=128)
            int c4  = (idx & 31) * 4;
            v[j] = *reinterpret_cast<const float4*>(
                &emb[(i0 + row) * D_EMB + k0 + c4]);
        }
        #pragma unroll
        for (int j = 0; j < 8; ++j) {
            int idx = j * 256 + t;
            int row = idx >> 5;
            int c4  = (idx & 31) * 4;
            u16x4 b = { f2b(v[j].x), f2b(v[j].y), f2b(v[j].z), f2b(v[j].w) };
            *reinterpret_cast<u16x4*>(&Ash[buf][row * LDAc + c4]) = b;
        }
    };

    f32x4 acc[4][2];
    #pragma unroll
    for (int rt = 0; rt < 4; ++rt) {
        acc[rt][0] = (f32x4){0.f, 0.f, 0.f, 0.f};
        acc[rt][1] = (f32x4){0.f, 0.f, 0.f, 0.f};
    }

    auto mfma_chunk = [&](int buf, bf16x8 (&bfr)[2][4]) {
        #pragma unroll
        for (int rt = 0; rt < 4; ++rt) {
            #pragma unroll
            for (int ks = 0; ks < 4; ++ks) {
                bf16x8 af = *reinterpret_cast<const bf16x8*>(
                    &Ash[buf][(16 * rt + l4) * LDAc + 32 * ks + 8 * h4]);
                acc[rt][0] = __builtin_amdgcn_mfma_f32_16x16x32_bf16(
                    af, bfr[0][ks], acc[rt][0], 0, 0, 0);
                acc[rt][1] = __builtin_amdgcn_mfma_f32_16x16x32_bf16(
                    af, bfr[1][ks], acc[rt][1], 0, 0, 0);
            }
        }
    };

    stage(0, 0);  loadB(bfA, 0);
    __syncthreads();
    stage(1, KC); loadB(bfB, KC);        // chunk 1 in flight
    mfma_chunk(0, bfA);
    __syncthreads();
    stage(0, 2 * KC); loadB(bfA, 2 * KC);
    mfma_chunk(1, bfB);
    __syncthreads();
    stage(1, 3 * KC); loadB(bfB, 3 * KC);
    mfma_chunk(0, bfA);
    __syncthreads();
    mfma_chunk(1, bfB);

    // epilogue: per-wave score partials (no atomics)
    // C layout: col = l4 + 16*(2w+nt), row = 16rt + 4h4 + reg (validated r2)
    #pragma unroll
    for (int rt = 0; rt < 4; ++rt) {
        #pragma unroll
        for (int reg = 0; reg < 4; ++reg) {
            float p = fast_tanh(acc[rt][0][reg] + ba1v[0]) * wo1v[0]
                    + fast_tanh(acc[rt][1][reg] + ba1v[1]) * wo1v[1];
            p += __shfl_xor(p, 1);
            p += __shfl_xor(p, 2);
            p += __shfl_xor(p, 4);
            p += __shfl_xor(p, 8);
            if (l4 == 0) att4[w][16 * rt + 4 * h4 + reg] = p;
        }
    }
    __syncthreads();
    if (t < TILE_I) {
        float a  = att4[0][t] + att4[1][t] + att4[2][t] + att4[3][t] + bo1[0];
        float sg = 1.f / (1.f + __expf(-a));   // in (0,1): exp needs no max-sub
        float s  = __expf(sg);
        sval_g[i0 + t] = s;
        float z = s;                           // wave-0 reduce for Z1
        #pragma unroll
        for (int m = 1; m < 64; m <<= 1) z += __shfl_xor(z, m);
        if (t == 0) atomicAdd(Z1, z);
    }
}

// ============ K_seg: weighted segment sum (streaming, L3-served re-read) ====
__global__ __launch_bounds__(256) void k_seg(
    const float* __restrict__ emb, const int* __restrict__ lab,
    const float* __restrict__ sval_g, float* __restrict__ rawr, int R)
{
    __shared__ float sv[TILE_I];
    __shared__ int   labs[TILE_I];
    const int t = threadIdx.x;
    const size_t i0 = (size_t)blockIdx.x * TILE_I;
    if (t < TILE_I) { sv[t] = sval_g[i0 + t]; labs[t] = lab[i0 + t]; }
    __syncthreads();
    float* __restrict__ raw = rawr + (size_t)(blockIdx.x % R) * (NBAGS * D_EMB);

    int s0 = 0;
    while (s0 < TILE_I) {
        int bag = labs[s0];
        int s1 = s0 + 1;
        while (s1 < TILE_I && labs[s1] == bag) ++s1;
        float a0 = 0.f, a1 = 0.f;
        const float* ebase = emb + (i0 + s0) * D_EMB + 2 * t;
        int len = s1 - s0;
        #pragma unroll 8
        for (int ii = 0; ii < len; ++ii) {
            float2 e = *reinterpret_cast<const float2*>(ebase + (size_t)ii * D_EMB);
            float s = sv[s0 + ii];
            a0 = fmaf(s, e.x, a0);
            a1 = fmaf(s, e.y, a1);
        }
        atomicAdd(&raw[bag * D_EMB + 2 * t], a0);
        atomicAdd(&raw[bag * D_EMB + 2 * t + 1], a1);
        s0 = s1;
    }
}

// ============ K2: replica-sum + normalize + bag-level attention ============
__global__ __launch_bounds__(128) void k_att2(
    const float* __restrict__ Wa2, const float* __restrict__ ba2,
    const float* __restrict__ wo2, const float* __restrict__ bo2,
    float* __restrict__ rawr, int R, const float* __restrict__ Z1,
    float* __restrict__ e2, float* __restrict__ Z2)
{
    __shared__ float sec[D_EMB];
    __shared__ float hh[2];
    const int b = blockIdx.x;
    const int t = threadIdx.x;
    const float zinv = 1.f / Z1[0];
    for (int d = t; d < D_EMB; d += 128) {
        float s = 0.f;
        for (int r = 0; r < R; ++r)
            s += rawr[(size_t)r * (NBAGS * D_EMB) + b * D_EMB + d];
        float v = s * zinv;
        rawr[b * D_EMB + d] = v;           // normalized into replica 0
        sec[d] = v;
    }
    __syncthreads();
    float dot = 0.f;
    #pragma unroll 8
    for (int d = 0; d < D_EMB; ++d) dot = fmaf(sec[d], Wa2[d * ATT + t], dot);
    float h = fast_tanh(dot + ba2[t]) * wo2[t];
    #pragma unroll
    for (int m = 1; m < 64; m <<= 1) h += __shfl_xor(h, m);
    if ((t & 63) == 0) hh[t >> 6] = h;
    __syncthreads();
    if (t == 0) {
        float a  = hh[0] + hh[1] + bo2[0];
        float sg = 1.f / (1.f + __expf(-a));
        float e  = __expf(sg);
        e2[b] = e;
        atomicAdd(Z2, e);
    }
}

// ============ Kv: v = W_c @ w_out ============
__global__ __launch_bounds__(256) void k_v(
    const float* __restrict__ Wc, const float* __restrict__ wout,
    float* __restrict__ v)
{
    const int t   = threadIdx.x;
    const int row = blockIdx.x * 8 + (t >> 5);
    const int l   = t & 31;
    float s = 0.f;
    #pragma unroll 4
    for (int c = l; c < 512; c += 32) s = fmaf(Wc[(size_t)row * 512 + c], wout[c], s);
    #pragma unroll
    for (int m = 1; m < 32; m <<= 1) s += __shfl_xor(s, m);
    if (l == 0) v[row] = s;
}

// ============ pool: outer_raw = sum_b e2[b] * raw0[b][:] (8 blocks) ===========
__global__ __launch_bounds__(256) void k_pool(
    const float* __restrict__ raw, const float* __restrict__ e2,
    float* __restrict__ outer)
{
    const int t  = threadIdx.x;
    const int b0 = blockIdx.x * 32;
    float o0 = 0.f, o1 = 0.f;
    for (int b = b0; b < b0 + 32; ++b) {
        float wgt = e2[b];
        float2 r = *reinterpret_cast<const float2*>(&raw[b * D_EMB + 2 * t]);
        o0 = fmaf(wgt, r.x, o0);
        o1 = fmaf(wgt, r.y, o1);
    }
    atomicAdd(&outer[2 * t], o0);
    atomicAdd(&outer[2 * t + 1], o1);
}

// ============ classifier: pred = sigmoid(outer/Z2 . v + bc . wout + bout) ====
__global__ __launch_bounds__(256) void k_cls(
    const float* __restrict__ outer, const float* __restrict__ Z2,
    const float* __restrict__ v, const float* __restrict__ bc,
    const float* __restrict__ wout, const float* __restrict__ bout,
    float* __restrict__ out)
{
    __shared__ float pp[4];
    const int t = threadIdx.x;
    const float z2inv = 1.f / Z2[0];
    float p = (outer[2 * t] * v[2 * t] + outer[2 * t + 1] * v[2 * t + 1]) * z2inv
            + bc[2 * t] * wout[2 * t] + bc[2 * t + 1] * wout[2 * t + 1];
    #pragma unroll
    for (int m = 1; m < 64; m <<= 1) p += __shfl_xor(p, m);
    if ((t & 63) == 0) pp[t >> 6] = p;
    __syncthreads();
    if (t == 0) {
        float s = pp[0] + pp[1] + pp[2] + pp[3] + bout[0];
        out[0] = 1.f / (1.f + __expf(-s));
    }
}

extern "C" void kernel_launch(void* const* d_in, const int* in_sizes, int n_in,
                              void* d_out, int out_size, void* d_ws, size_t ws_size,
                              hipStream_t stream)
{
    const float* emb  = (const float*)d_in[0];
    const int*   lab  = (const int*)d_in[1];
    const float* Wa1  = (const float*)d_in[2];
    const float* ba1  = (const float*)d_in[3];
    const float* wo1  = (const float*)d_in[4];
    const float* bo1  = (const float*)d_in[5];
    const float* Wa2  = (const float*)d_in[6];
    const float* ba2  = (const float*)d_in[7];
    const float* wo2  = (const float*)d_in[8];
    const float* bo2  = (const float*)d_in[9];
    const float* Wc   = (const float*)d_in[10];
    const float* bc   = (const float*)d_in[11];
    const float* wout = (const float*)d_in[12];
    const float* bout = (const float*)d_in[13];

    float* ws     = (float*)d_ws;
    float* Z1     = ws + 0;
    float* Z2     = ws + 1;
    float* v      = ws + 16;
    float* e2     = ws + 1024;
    float* outer  = ws + 1536;
    unsigned short* Wt = (unsigned short*)(ws + 4096);
    float* rawr   = ws + 36864;
    float* sval_g = ws + 1085440;

    // replica count: 8 if workspace allows (XCD-local atomics), else 1
    const size_t need8 = ((size_t)1085440 + N_INST) * sizeof(float);
    const int R = (ws_size >= need8) ? 8 : 1;
    float* sval = (R == 8) ? sval_g : ws + 36864 + NBAGS * D_EMB;

    // zero scalars + replica accumulators (harness does not re-poison)
    hipMemsetAsync(d_ws, 0, ((size_t)36864 + (size_t)R * NBAGS * D_EMB) * sizeof(float), stream);

    hipLaunchKernelGGL(k_prep_wt, dim3(ATT),             dim3(256), 0, stream, Wa1, Wt);
    hipLaunchKernelGGL(k_v,       dim3(64),              dim3(256), 0, stream, Wc, wout, v);
    hipLaunchKernelGGL(k_score,   dim3(N_INST / TILE_I), dim3(256), 0, stream,
                       emb, Wt, ba1, wo1, bo1, sval, Z1);
    hipLaunchKernelGGL(k_seg,     dim3(N_INST / TILE_I), dim3(256), 0, stream,
                       emb, lab, sval, rawr, R);
    hipLaunchKernelGGL(k_att2,    dim3(NBAGS),           dim3(128), 0, stream,
                       Wa2, ba2, wo2, bo2, rawr, R, Z1, e2, Z2);
    hipLaunchKernelGGL(k_pool,    dim3(8),               dim3(256), 0, stream,
                       rawr, e2, outer);
    hipLaunchKernelGGL(k_cls,     dim3(1),               dim3(256), 0, stream,
                       outer, Z2, v, bc, wout, bout, (float*)d_out);
}

// Round 7
// 166.348 us; speedup vs baseline: 1.0347x; 1.0347x over previous
//
#include <hip/hip_runtime.h>
#include <cstdint>
#include <cstddef>

#define N_INST 131072
#define D_EMB  512
#define ATT    128
#define NBAGS  256
#define TILE_I 32
#define LDA    520  // padded bf16 row stride (1040 B): phase-2 dword reads 2-way (free)

typedef __attribute__((ext_vector_type(8))) short  bf16x8;
typedef __attribute__((ext_vector_type(4))) float  f32x4;
typedef __attribute__((ext_vector_type(4))) unsigned short u16x4;

// ---------------- workspace layout (floats) ----------------
// [0] Z1, [1] Z2
// [16..528)     v[512]     = W_c @ w_out (folded classifier)
// [1024..1280)  e2[256]
// [1536..2048)  outer[512]
// [4096..36864) Wt bf16 [128][512] (W_a1 transposed, n-major; 65536 bf16)
// [36864..1085440)  rawr[8][256][512]  (replica-sharded bag accumulators)

__device__ inline unsigned short f2b(float f) {
    unsigned u = __builtin_bit_cast(unsigned, f);
    u += 0x7FFFu + ((u >> 16) & 1u);          // RNE
    return (unsigned short)(u >> 16);
}

__device__ inline float fast_tanh(float x) {
    float e = __expf(2.f * x);                // +inf/0 at extremes -> exact +-1
    return 1.f - 2.f / (e + 1.f);
}

// ============ prep: Wt[n][k] = bf16(W_a1[k][n]) ============
__global__ __launch_bounds__(256) void k_prep_wt(
    const float* __restrict__ Wa1, unsigned short* __restrict__ Wt)
{
    const int n = blockIdx.x;
    for (int k = threadIdx.x; k < D_EMB; k += 256)
        Wt[(size_t)n * D_EMB + k] = f2b(Wa1[(size_t)k * ATT + n]);
}

// ============ K1: fused scores + weighted segment sum, 32 inst/block =========
// 4 waves; wave w owns n-cols [32w,32w+32) (2 n-tiles), all 32 rows.
// Ash 33 KB -> 4 blocks/CU, 16 waves/CU: staggered block tails keep HBM busy.
__global__ __launch_bounds__(256, 4) void k_att1(
    const float* __restrict__ emb, const int* __restrict__ lab,
    const unsigned short* __restrict__ Wt, const float* __restrict__ ba1,
    const float* __restrict__ wo1, const float* __restrict__ bo1,
    float* __restrict__ rawr, int R, float* __restrict__ Z1)
{
    __shared__ unsigned short Ash[TILE_I * LDA];   // 33280 B
    __shared__ float att4[4][TILE_I];
    __shared__ float sval[TILE_I];
    __shared__ int   labs[TILE_I];

    const int t  = threadIdx.x;
    const int w  = t >> 6;        // 0..3
    const int l  = t & 63;
    const int l4 = l & 15;
    const int h4 = l >> 4;        // 0..3
    const size_t i0 = (size_t)blockIdx.x * TILE_I;
    float* __restrict__ raw = rawr + (size_t)(blockIdx.x % R) * (NBAGS * D_EMB);

    if (t < TILE_I) labs[t] = lab[i0 + t];

    float ba1v[2], wo1v[2];
    #pragma unroll
    for (int nt = 0; nt < 2; ++nt) {
        int c = 16 * (2 * w + nt) + l4;
        ba1v[nt] = ba1[c];
        wo1v[nt] = wo1[c];
    }

    // B fragments (compiler rematerializes from L2-hot Wt if VGPR-tight)
    bf16x8 bfrag[2][16];
    #pragma unroll
    for (int nt = 0; nt < 2; ++nt) {
        const int n = 16 * (2 * w + nt) + l4;
        #pragma unroll
        for (int ks = 0; ks < 16; ++ks)
            bfrag[nt][ks] = *reinterpret_cast<const bf16x8*>(
                &Wt[(size_t)n * D_EMB + 32 * ks + 8 * h4]);
    }

    // ---- stage A: 32 rows x 512 k fp32 -> bf16 LDS, 2 bursts of 8 ----
    #pragma unroll
    for (int g = 0; g < 2; ++g) {
        float4 v[8];
        #pragma unroll
        for (int j = 0; j < 8; ++j) {
            int idx = (g * 8 + j) * 256 + t;     // float4 idx in [0, 4096)
            int row = idx >> 7;                  // 128 float4 per row
            int c4  = (idx & 127) * 4;
            v[j] = *reinterpret_cast<const float4*>(&emb[(i0 + row) * D_EMB + c4]);
        }
        #pragma unroll
        for (int j = 0; j < 8; ++j) {
            int idx = (g * 8 + j) * 256 + t;
            int row = idx >> 7;
            int c4  = (idx & 127) * 4;
            u16x4 b = { f2b(v[j].x), f2b(v[j].y), f2b(v[j].z), f2b(v[j].w) };
            *reinterpret_cast<u16x4*>(&Ash[row * LDA + c4]) = b;
        }
    }
    __syncthreads();   // the only staging barrier

    // ---- score GEMM: 32 ds_read_b128 + 64 MFMA per wave ----
    f32x4 acc[2][2];
    #pragma unroll
    for (int rt = 0; rt < 2; ++rt) {
        acc[rt][0] = (f32x4){0.f, 0.f, 0.f, 0.f};
        acc[rt][1] = (f32x4){0.f, 0.f, 0.f, 0.f};
    }
    #pragma unroll
    for (int rt = 0; rt < 2; ++rt) {
        #pragma unroll
        for (int ks = 0; ks < 16; ++ks) {
            bf16x8 af = *reinterpret_cast<const bf16x8*>(
                &Ash[(16 * rt + l4) * LDA + 32 * ks + 8 * h4]);
            acc[rt][0] = __builtin_amdgcn_mfma_f32_16x16x32_bf16(
                af, bfrag[0][ks], acc[rt][0], 0, 0, 0);
            acc[rt][1] = __builtin_amdgcn_mfma_f32_16x16x32_bf16(
                af, bfrag[1][ks], acc[rt][1], 0, 0, 0);
        }
    }

    // ---- epilogue: per-wave score partials (no atomics) ----
    // C layout: col = l4 + 16*(2w+nt), row = 16rt + 4h4 + reg (validated r2)
    #pragma unroll
    for (int rt = 0; rt < 2; ++rt) {
        #pragma unroll
        for (int reg = 0; reg < 4; ++reg) {
            float p = fast_tanh(acc[rt][0][reg] + ba1v[0]) * wo1v[0]
                    + fast_tanh(acc[rt][1][reg] + ba1v[1]) * wo1v[1];
            p += __shfl_xor(p, 1);
            p += __shfl_xor(p, 2);
            p += __shfl_xor(p, 4);
            p += __shfl_xor(p, 8);
            if (l4 == 0) att4[w][16 * rt + 4 * h4 + reg] = p;
        }
    }
    __syncthreads();
    if (t < TILE_I) {
        float a  = att4[0][t] + att4[1][t] + att4[2][t] + att4[3][t] + bo1[0];
        float sg = 1.f / (1.f + __expf(-a));   // in (0,1): exp needs no max-sub
        sval[t]  = __expf(sg);
    }
    __syncthreads();
    if (t < TILE_I) {                          // lanes 0..31 of wave 0
        float z = sval[t];
        z += __shfl_xor(z, 1);
        z += __shfl_xor(z, 2);
        z += __shfl_xor(z, 4);
        z += __shfl_xor(z, 8);
        z += __shfl_xor(z, 16);
        if (t == 0) atomicAdd(Z1, z);
    }

    // ---- phase 2: weighted segment sum from LDS (bf16 -> f32 unpack) ----
    // thread t owns dims {2t, 2t+1}; dword reads stride-1 across lanes (free).
    int s0 = 0;
    while (s0 < TILE_I) {
        int bag = labs[s0];
        int s1 = s0 + 1;
        while (s1 < TILE_I && labs[s1] == bag) ++s1;
        float a0 = 0.f, a1 = 0.f;
        #pragma unroll 8
        for (int ii = s0; ii < s1; ++ii) {
            unsigned u = *reinterpret_cast<const unsigned*>(
                &Ash[(size_t)ii * LDA + 2 * t]);
            float lo = __builtin_bit_cast(float, u << 16);
            float hi = __builtin_bit_cast(float, u & 0xffff0000u);
            float s  = sval[ii];
            a0 = fmaf(s, lo, a0);
            a1 = fmaf(s, hi, a1);
        }
        atomicAdd(&raw[bag * D_EMB + 2 * t], a0);
        atomicAdd(&raw[bag * D_EMB + 2 * t + 1], a1);
        s0 = s1;
    }
}

// ============ K2: replica-sum + normalize + bag-level attention ============
__global__ __launch_bounds__(128) void k_att2(
    const float* __restrict__ Wa2, const float* __restrict__ ba2,
    const float* __restrict__ wo2, const float* __restrict__ bo2,
    float* __restrict__ rawr, int R, const float* __restrict__ Z1,
    float* __restrict__ e2, float* __restrict__ Z2)
{
    __shared__ float sec[D_EMB];
    __shared__ float hh[2];
    const int b = blockIdx.x;
    const int t = threadIdx.x;
    const float zinv = 1.f / Z1[0];
    for (int d = t; d < D_EMB; d += 128) {
        float s = 0.f;
        for (int r = 0; r < R; ++r)
            s += rawr[(size_t)r * (NBAGS * D_EMB) + b * D_EMB + d];
        float v = s * zinv;
        rawr[b * D_EMB + d] = v;           // normalized into replica 0
        sec[d] = v;
    }
    __syncthreads();
    float dot = 0.f;
    #pragma unroll 8
    for (int d = 0; d < D_EMB; ++d) dot = fmaf(sec[d], Wa2[d * ATT + t], dot);
    float h = fast_tanh(dot + ba2[t]) * wo2[t];
    #pragma unroll
    for (int m = 1; m < 64; m <<= 1) h += __shfl_xor(h, m);
    if ((t & 63) == 0) hh[t >> 6] = h;
    __syncthreads();
    if (t == 0) {
        float a  = hh[0] + hh[1] + bo2[0];
        float sg = 1.f / (1.f + __expf(-a));
        float e  = __expf(sg);
        e2[b] = e;
        atomicAdd(Z2, e);
    }
}

// ============ Kv: v = W_c @ w_out ============
__global__ __launch_bounds__(256) void k_v(
    const float* __restrict__ Wc, const float* __restrict__ wout,
    float* __restrict__ v)
{
    const int t   = threadIdx.x;
    const int row = blockIdx.x * 8 + (t >> 5);
    const int l   = t & 31;
    float s = 0.f;
    #pragma unroll 4
    for (int c = l; c < 512; c += 32) s = fmaf(Wc[(size_t)row * 512 + c], wout[c], s);
    #pragma unroll
    for (int m = 1; m < 32; m <<= 1) s += __shfl_xor(s, m);
    if (l == 0) v[row] = s;
}

// ============ pool: outer_raw = sum_b e2[b] * raw0[b][:] (8 blocks) ===========
__global__ __launch_bounds__(256) void k_pool(
    const float* __restrict__ raw, const float* __restrict__ e2,
    float* __restrict__ outer)
{
    const int t  = threadIdx.x;
    const int b0 = blockIdx.x * 32;
    float o0 = 0.f, o1 = 0.f;
    for (int b = b0; b < b0 + 32; ++b) {
        float wgt = e2[b];
        float2 r = *reinterpret_cast<const float2*>(&raw[b * D_EMB + 2 * t]);
        o0 = fmaf(wgt, r.x, o0);
        o1 = fmaf(wgt, r.y, o1);
    }
    atomicAdd(&outer[2 * t], o0);
    atomicAdd(&outer[2 * t + 1], o1);
}

// ============ classifier: pred = sigmoid(outer/Z2 . v + bc . wout + bout) ====
__global__ __launch_bounds__(256) void k_cls(
    const float* __restrict__ outer, const float* __restrict__ Z2,
    const float* __restrict__ v, const float* __restrict__ bc,
    const float* __restrict__ wout, const float* __restrict__ bout,
    float* __restrict__ out)
{
    __shared__ float pp[4];
    const int t = threadIdx.x;
    const float z2inv = 1.f / Z2[0];
    float p = (outer[2 * t] * v[2 * t] + outer[2 * t + 1] * v[2 * t + 1]) * z2inv
            + bc[2 * t] * wout[2 * t] + bc[2 * t + 1] * wout[2 * t + 1];
    #pragma unroll
    for (int m = 1; m < 64; m <<= 1) p += __shfl_xor(p, m);
    if ((t & 63) == 0) pp[t >> 6] = p;
    __syncthreads();
    if (t == 0) {
        float s = pp[0] + pp[1] + pp[2] + pp[3] + bout[0];
        out[0] = 1.f / (1.f + __expf(-s));
    }
}

extern "C" void kernel_launch(void* const* d_in, const int* in_sizes, int n_in,
                              void* d_out, int out_size, void* d_ws, size_t ws_size,
                              hipStream_t stream)
{
    const float* emb  = (const float*)d_in[0];
    const int*   lab  = (const int*)d_in[1];
    const float* Wa1  = (const float*)d_in[2];
    const float* ba1  = (const float*)d_in[3];
    const float* wo1  = (const float*)d_in[4];
    const float* bo1  = (const float*)d_in[5];
    const float* Wa2  = (const float*)d_in[6];
    const float* ba2  = (const float*)d_in[7];
    const float* wo2  = (const float*)d_in[8];
    const float* bo2  = (const float*)d_in[9];
    const float* Wc   = (const float*)d_in[10];
    const float* bc   = (const float*)d_in[11];
    const float* wout = (const float*)d_in[12];
    const float* bout = (const float*)d_in[13];

    float* ws    = (float*)d_ws;
    float* Z1    = ws + 0;
    float* Z2    = ws + 1;
    float* v     = ws + 16;
    float* e2    = ws + 1024;
    float* outer = ws + 1536;
    unsigned short* Wt = (unsigned short*)(ws + 4096);
    float* rawr  = ws + 36864;

    // replica count: 8 if workspace allows (XCD-local atomics), else 1
    const size_t need8 = ((size_t)36864 + 8u * NBAGS * D_EMB) * sizeof(float);
    const int R = (ws_size >= need8) ? 8 : 1;

    // zero scalars + replica accumulators (harness does not re-poison)
    hipMemsetAsync(d_ws, 0, ((size_t)36864 + (size_t)R * NBAGS * D_EMB) * sizeof(float), stream);

    hipLaunchKernelGGL(k_prep_wt, dim3(ATT),             dim3(256), 0, stream, Wa1, Wt);
    hipLaunchKernelGGL(k_v,       dim3(64),              dim3(256), 0, stream, Wc, wout, v);
    hipLaunchKernelGGL(k_att1,    dim3(N_INST / TILE_I), dim3(256), 0, stream,
                       emb, lab, Wt, ba1, wo1, bo1, rawr, R, Z1);
    hipLaunchKernelGGL(k_att2,    dim3(NBAGS),           dim3(128), 0, stream,
                       Wa2, ba2, wo2, bo2, rawr, R, Z1, e2, Z2);
    hipLaunchKernelGGL(k_pool,    dim3(8),               dim3(256), 0, stream,
                       rawr, e2, outer);
    hipLaunchKernelGGL(k_cls,     dim3(1),               dim3(256), 0, stream,
                       outer, Z2, v, bc, wout, bout, (float*)d_out);
}

// Round 8
// 135.960 us; speedup vs baseline: 1.2660x; 1.2235x over previous
//
#include <hip/hip_runtime.h>
#include <cstdint>
#include <cstddef>

#define N_INST 131072
#define D_EMB  512
#define ATT    128
#define NBAGS  256
#define TILE_I 32
#define LDA    520   // padded bf16 row stride (1040 B)
#define NBLK   512   // persistent blocks (2 per CU)
#define NTILES (N_INST / TILE_I)   // 4096
#define TPB    (NTILES / NBLK)     // 8 tiles per block

typedef __attribute__((ext_vector_type(8))) short  bf16x8;
typedef __attribute__((ext_vector_type(4))) float  f32x4;
typedef __attribute__((ext_vector_type(4))) unsigned short u16x4;

// ---------------- workspace layout (floats) ----------------
// [0] Z1, [1] Z2
// [16..528)     v[512]     = W_c @ w_out (folded classifier)
// [1024..1280)  e2[256]
// [1536..2048)  outer[512]
// [4096..36864) Wt bf16 [128][512] (W_a1 transposed, n-major; 65536 bf16)
// [36864..1085440)  rawr[8][256][512]  (replica-sharded bag accumulators)

__device__ inline unsigned short f2b(float f) {
    unsigned u = __builtin_bit_cast(unsigned, f);
    u += 0x7FFFu + ((u >> 16) & 1u);          // RNE
    return (unsigned short)(u >> 16);
}

__device__ inline float fast_tanh(float x) {
    float e = __expf(2.f * x);                // +inf/0 at extremes -> exact +-1
    return 1.f - 2.f / (e + 1.f);
}

// ============ prep: Wt[n][k] = bf16(W_a1[k][n]) ============
__global__ __launch_bounds__(256) void k_prep_wt(
    const float* __restrict__ Wa1, unsigned short* __restrict__ Wt)
{
    const int n = blockIdx.x;
    for (int k = threadIdx.x; k < D_EMB; k += 256)
        Wt[(size_t)n * D_EMB + k] = f2b(Wa1[(size_t)k * ATT + n]);
}

// ============ K1: persistent, double-buffered fused attention ============
// 512 persistent blocks x 8 tiles of 32 instances. Per iteration: issue next
// tile's global loads FIRST (in flight across ~3K cycles of compute), then
// GEMM + epilogue + phase-2 on current LDS buffer, then cvt+ds_write the
// prefetched data into the other buffer. B loaded per-ks from L2-hot Wt
// (NOT register-resident: keeps VGPR < 256, no scratch spill -- r7 lesson).
__global__ __launch_bounds__(256, 2) void k_att1(
    const float* __restrict__ emb, const int* __restrict__ lab,
    const unsigned short* __restrict__ Wt, const float* __restrict__ ba1,
    const float* __restrict__ wo1, const float* __restrict__ bo1,
    float* __restrict__ rawr, int R, float* __restrict__ Z1)
{
    __shared__ unsigned short Ash[2][TILE_I * LDA];   // 2 x 33280 B
    __shared__ float att4[4][TILE_I];
    __shared__ float sval[TILE_I];
    __shared__ int   labs[2][TILE_I];

    const int t  = threadIdx.x;
    const int w  = t >> 6;        // 0..3: wave owns n-cols [32w, 32w+32)
    const int l  = t & 63;
    const int l4 = l & 15;
    const int h4 = l >> 4;        // 0..3
    const int n0 = 16 * (2 * w) + l4;       // this lane's two output columns
    const int n1 = 16 * (2 * w + 1) + l4;
    float* __restrict__ raw = rawr + (size_t)(blockIdx.x % R) * (NBAGS * D_EMB);

    const float ba1v0 = ba1[n0], ba1v1 = ba1[n1];
    const float wo1v0 = wo1[n0], wo1v1 = wo1[n1];
    float z1acc = 0.f;

    // ---- prologue: stage tile 0 into buf 0 ----
    {
        const size_t i0 = (size_t)blockIdx.x * TILE_I;
        float4 v[16];
        #pragma unroll
        for (int j = 0; j < 16; ++j) {
            int idx = j * 256 + t;           // float4 idx in [0, 4096)
            int row = idx >> 7;              // 128 float4 per row
            int c4  = (idx & 127) * 4;
            v[j] = *reinterpret_cast<const float4*>(&emb[(i0 + row) * D_EMB + c4]);
        }
        if (t < TILE_I) labs[0][t] = lab[i0 + t];
        #pragma unroll
        for (int j = 0; j < 16; ++j) {
            int idx = j * 256 + t;
            int row = idx >> 7;
            int c4  = (idx & 127) * 4;
            u16x4 b = { f2b(v[j].x), f2b(v[j].y), f2b(v[j].z), f2b(v[j].w) };
            *reinterpret_cast<u16x4*>(&Ash[0][row * LDA + c4]) = b;
        }
    }
    __syncthreads();

    int p = 0;
    for (int it = 0; it < TPB; ++it) {
        const bool hasNext = (it + 1 < TPB);
        const size_t i0n = ((size_t)blockIdx.x + (size_t)(it + 1) * NBLK) * TILE_I;

        // ---- (1) issue next tile's loads (stay in flight through compute) --
        float4 v[16];
        int nlab = 0;
        if (hasNext) {
            #pragma unroll
            for (int j = 0; j < 16; ++j) {
                int idx = j * 256 + t;
                int row = idx >> 7;
                int c4  = (idx & 127) * 4;
                v[j] = *reinterpret_cast<const float4*>(
                    &emb[(i0n + row) * D_EMB + c4]);
            }
            if (t < TILE_I) nlab = lab[i0n + t];
        }

        // ---- (2) score GEMM on Ash[p]; B per-ks from L2-hot Wt ----
        f32x4 acc00 = {0.f,0.f,0.f,0.f}, acc01 = {0.f,0.f,0.f,0.f};
        f32x4 acc10 = {0.f,0.f,0.f,0.f}, acc11 = {0.f,0.f,0.f,0.f};
        #pragma unroll
        for (int ks = 0; ks < 16; ++ks) {
            bf16x8 b0 = *reinterpret_cast<const bf16x8*>(
                &Wt[(size_t)n0 * D_EMB + 32 * ks + 8 * h4]);
            bf16x8 b1 = *reinterpret_cast<const bf16x8*>(
                &Wt[(size_t)n1 * D_EMB + 32 * ks + 8 * h4]);
            bf16x8 a0 = *reinterpret_cast<const bf16x8*>(
                &Ash[p][(l4) * LDA + 32 * ks + 8 * h4]);
            bf16x8 a1 = *reinterpret_cast<const bf16x8*>(
                &Ash[p][(16 + l4) * LDA + 32 * ks + 8 * h4]);
            acc00 = __builtin_amdgcn_mfma_f32_16x16x32_bf16(a0, b0, acc00, 0, 0, 0);
            acc01 = __builtin_amdgcn_mfma_f32_16x16x32_bf16(a0, b1, acc01, 0, 0, 0);
            acc10 = __builtin_amdgcn_mfma_f32_16x16x32_bf16(a1, b0, acc10, 0, 0, 0);
            acc11 = __builtin_amdgcn_mfma_f32_16x16x32_bf16(a1, b1, acc11, 0, 0, 0);
        }

        // ---- (3) epilogue: per-wave score partials ----
        // C layout: col = l4 + 16*(2w+nt), row = 16rt + 4h4 + reg (validated r2)
        #pragma unroll
        for (int rt = 0; rt < 2; ++rt) {
            #pragma unroll
            for (int reg = 0; reg < 4; ++reg) {
                float pp = fast_tanh((rt ? acc10[reg] : acc00[reg]) + ba1v0) * wo1v0
                         + fast_tanh((rt ? acc11[reg] : acc01[reg]) + ba1v1) * wo1v1;
                pp += __shfl_xor(pp, 1);
                pp += __shfl_xor(pp, 2);
                pp += __shfl_xor(pp, 4);
                pp += __shfl_xor(pp, 8);
                if (l4 == 0) att4[w][16 * rt + 4 * h4 + reg] = pp;
            }
        }
        __syncthreads();                                   // B1
        if (t < TILE_I) {
            float a  = att4[0][t] + att4[1][t] + att4[2][t] + att4[3][t] + bo1[0];
            float sg = 1.f / (1.f + __expf(-a));   // in (0,1): exp needs no max-sub
            sval[t]  = __expf(sg);
        }
        __syncthreads();                                   // B2
        if (t < TILE_I) {                                  // lanes 0..31, wave 0
            float z = sval[t];
            z += __shfl_xor(z, 1);
            z += __shfl_xor(z, 2);
            z += __shfl_xor(z, 4);
            z += __shfl_xor(z, 8);
            z += __shfl_xor(z, 16);
            if (t == 0) z1acc += z;
        }

        // ---- (4) phase 2: weighted segment sum from Ash[p] ----
        int s0 = 0;
        while (s0 < TILE_I) {
            int bag = labs[p][s0];
            int s1 = s0 + 1;
            while (s1 < TILE_I && labs[p][s1] == bag) ++s1;
            float a0 = 0.f, a1 = 0.f;
            for (int ii = s0; ii < s1; ++ii) {
                unsigned u = *reinterpret_cast<const unsigned*>(
                    &Ash[p][(size_t)ii * LDA + 2 * t]);
                float lo = __builtin_bit_cast(float, u << 16);
                float hi = __builtin_bit_cast(float, u & 0xffff0000u);
                float s  = sval[ii];
                a0 = fmaf(s, lo, a0);
                a1 = fmaf(s, hi, a1);
            }
            atomicAdd(&raw[bag * D_EMB + 2 * t], a0);
            atomicAdd(&raw[bag * D_EMB + 2 * t + 1], a1);
            s0 = s1;
        }
        __syncthreads();                                   // B3: Ash[p] free

        // ---- (5) write prefetched tile into Ash[p^1] ----
        if (hasNext) {
            #pragma unroll
            for (int j = 0; j < 16; ++j) {
                int idx = j * 256 + t;
                int row = idx >> 7;
                int c4  = (idx & 127) * 4;
                u16x4 b = { f2b(v[j].x), f2b(v[j].y), f2b(v[j].z), f2b(v[j].w) };
                *reinterpret_cast<u16x4*>(&Ash[p ^ 1][row * LDA + c4]) = b;
            }
            if (t < TILE_I) labs[p ^ 1][t] = nlab;
        }
        __syncthreads();                                   // B4: buffer ready
        p ^= 1;
    }
    if (t == 0) atomicAdd(Z1, z1acc);
}

// ============ K2: replica-sum + normalize + bag-level attention ============
__global__ __launch_bounds__(128) void k_att2(
    const float* __restrict__ Wa2, const float* __restrict__ ba2,
    const float* __restrict__ wo2, const float* __restrict__ bo2,
    float* __restrict__ rawr, int R, const float* __restrict__ Z1,
    float* __restrict__ e2, float* __restrict__ Z2)
{
    __shared__ float sec[D_EMB];
    __shared__ float hh[2];
    const int b = blockIdx.x;
    const int t = threadIdx.x;
    const float zinv = 1.f / Z1[0];
    for (int d = t; d < D_EMB; d += 128) {
        float s = 0.f;
        for (int r = 0; r < R; ++r)
            s += rawr[(size_t)r * (NBAGS * D_EMB) + b * D_EMB + d];
        float v = s * zinv;
        rawr[b * D_EMB + d] = v;           // normalized into replica 0
        sec[d] = v;
    }
    __syncthreads();
    float dot = 0.f;
    #pragma unroll 8
    for (int d = 0; d < D_EMB; ++d) dot = fmaf(sec[d], Wa2[d * ATT + t], dot);
    float h = fast_tanh(dot + ba2[t]) * wo2[t];
    #pragma unroll
    for (int m = 1; m < 64; m <<= 1) h += __shfl_xor(h, m);
    if ((t & 63) == 0) hh[t >> 6] = h;
    __syncthreads();
    if (t == 0) {
        float a  = hh[0] + hh[1] + bo2[0];
        float sg = 1.f / (1.f + __expf(-a));
        float e  = __expf(sg);
        e2[b] = e;
        atomicAdd(Z2, e);
    }
}

// ============ Kv: v = W_c @ w_out ============
__global__ __launch_bounds__(256) void k_v(
    const float* __restrict__ Wc, const float* __restrict__ wout,
    float* __restrict__ v)
{
    const int t   = threadIdx.x;
    const int row = blockIdx.x * 8 + (t >> 5);
    const int l   = t & 31;
    float s = 0.f;
    #pragma unroll 4
    for (int c = l; c < 512; c += 32) s = fmaf(Wc[(size_t)row * 512 + c], wout[c], s);
    #pragma unroll
    for (int m = 1; m < 32; m <<= 1) s += __shfl_xor(s, m);
    if (l == 0) v[row] = s;
}

// ============ pool: outer_raw = sum_b e2[b] * raw0[b][:] (8 blocks) ===========
__global__ __launch_bounds__(256) void k_pool(
    const float* __restrict__ raw, const float* __restrict__ e2,
    float* __restrict__ outer)
{
    const int t  = threadIdx.x;
    const int b0 = blockIdx.x * 32;
    float o0 = 0.f, o1 = 0.f;
    for (int b = b0; b < b0 + 32; ++b) {
        float wgt = e2[b];
        float2 r = *reinterpret_cast<const float2*>(&raw[b * D_EMB + 2 * t]);
        o0 = fmaf(wgt, r.x, o0);
        o1 = fmaf(wgt, r.y, o1);
    }
    atomicAdd(&outer[2 * t], o0);
    atomicAdd(&outer[2 * t + 1], o1);
}

// ============ classifier: pred = sigmoid(outer/Z2 . v + bc . wout + bout) ====
__global__ __launch_bounds__(256) void k_cls(
    const float* __restrict__ outer, const float* __restrict__ Z2,
    const float* __restrict__ v, const float* __restrict__ bc,
    const float* __restrict__ wout, const float* __restrict__ bout,
    float* __restrict__ out)
{
    __shared__ float pp[4];
    const int t = threadIdx.x;
    const float z2inv = 1.f / Z2[0];
    float p = (outer[2 * t] * v[2 * t] + outer[2 * t + 1] * v[2 * t + 1]) * z2inv
            + bc[2 * t] * wout[2 * t] + bc[2 * t + 1] * wout[2 * t + 1];
    #pragma unroll
    for (int m = 1; m < 64; m <<= 1) p += __shfl_xor(p, m);
    if ((t & 63) == 0) pp[t >> 6] = p;
    __syncthreads();
    if (t == 0) {
        float s = pp[0] + pp[1] + pp[2] + pp[3] + bout[0];
        out[0] = 1.f / (1.f + __expf(-s));
    }
}

extern "C" void kernel_launch(void* const* d_in, const int* in_sizes, int n_in,
                              void* d_out, int out_size, void* d_ws, size_t ws_size,
                              hipStream_t stream)
{
    const float* emb  = (const float*)d_in[0];
    const int*   lab  = (const int*)d_in[1];
    const float* Wa1  = (const float*)d_in[2];
    const float* ba1  = (const float*)d_in[3];
    const float* wo1  = (const float*)d_in[4];
    const float* bo1  = (const float*)d_in[5];
    const float* Wa2  = (const float*)d_in[6];
    const float* ba2  = (const float*)d_in[7];
    const float* wo2  = (const float*)d_in[8];
    const float* bo2  = (const float*)d_in[9];
    const float* Wc   = (const float*)d_in[10];
    const float* bc   = (const float*)d_in[11];
    const float* wout = (const float*)d_in[12];
    const float* bout = (const float*)d_in[13];

    float* ws    = (float*)d_ws;
    float* Z1    = ws + 0;
    float* Z2    = ws + 1;
    float* v     = ws + 16;
    float* e2    = ws + 1024;
    float* outer = ws + 1536;
    unsigned short* Wt = (unsigned short*)(ws + 4096);
    float* rawr  = ws + 36864;

    // replica count: 8 if workspace allows (XCD-local atomics), else 1
    const size_t need8 = ((size_t)36864 + 8u * NBAGS * D_EMB) * sizeof(float);
    const int R = (ws_size >= need8) ? 8 : 1;

    // zero scalars + replica accumulators (harness does not re-poison)
    hipMemsetAsync(d_ws, 0, ((size_t)36864 + (size_t)R * NBAGS * D_EMB) * sizeof(float), stream);

    hipLaunchKernelGGL(k_prep_wt, dim3(ATT),   dim3(256), 0, stream, Wa1, Wt);
    hipLaunchKernelGGL(k_v,       dim3(64),    dim3(256), 0, stream, Wc, wout, v);
    hipLaunchKernelGGL(k_att1,    dim3(NBLK),  dim3(256), 0, stream,
                       emb, lab, Wt, ba1, wo1, bo1, rawr, R, Z1);
    hipLaunchKernelGGL(k_att2,    dim3(NBAGS), dim3(128), 0, stream,
                       Wa2, ba2, wo2, bo2, rawr, R, Z1, e2, Z2);
    hipLaunchKernelGGL(k_pool,    dim3(8),     dim3(256), 0, stream,
                       rawr, e2, outer);
    hipLaunchKernelGGL(k_cls,     dim3(1),     dim3(256), 0, stream,
                       outer, Z2, v, bc, wout, bout, (float*)d_out);
}